// Round 3
// baseline (14327.681 us; speedup 1.0000x reference)
//
#include <hip/hip_runtime.h>

typedef unsigned short u16;
typedef short bf16x8 __attribute__((ext_vector_type(8)));
typedef float f32x4 __attribute__((ext_vector_type(4)));

#define SS 2048   // sequence length
#define BB 64     // batch
#define HH 512    // hidden
#define GG 2048   // 4*H gates

// ws layout (bytes)
#define WB_ELEMS (2048 * 1024)            // packed bf16 weight frags (4 MB)
#define OFF_BIAS ((size_t)WB_ELEMS * 2)   // 4,194,304
#define OFF_H0   (OFF_BIAS + 2048 * 4)    // 4,202,496  (h slot0, bf16 [64][512])
#define OFF_H1   (OFF_H0 + 32768 * 2)     // 4,268,032  (h slot1)
#define OFF_FLG  (OFF_H1 + 32768 * 2)     // 4,333,568  (512 wave flags, u32)
#define WS_BASE  (OFF_FLG + 2048)         // 4,335,616
#define OFF_XBF  WS_BASE                  // optional bf16 x (128 MB)
#define WS_XBF   (OFF_XBF + (size_t)SS * BB * 512 * 2)   // 138,553,344

__device__ __forceinline__ u16 f2bf(float f) {
    unsigned int u = __builtin_bit_cast(unsigned int, f);
    u += 0x7FFFu + ((u >> 16) & 1u);   // round-to-nearest-even
    return (u16)(u >> 16);
}

// 8x f32 -> bf16x8 via v_cvt_pk_bf16_f32 (RNE)
__device__ __forceinline__ bf16x8 pack8(float4 fa, float4 fb) {
    union { unsigned u[4]; bf16x8 v; } r;
    asm("v_cvt_pk_bf16_f32 %0, %1, %2" : "=v"(r.u[0]) : "v"(fa.x), "v"(fa.y));
    asm("v_cvt_pk_bf16_f32 %0, %1, %2" : "=v"(r.u[1]) : "v"(fa.z), "v"(fa.w));
    asm("v_cvt_pk_bf16_f32 %0, %1, %2" : "=v"(r.u[2]) : "v"(fb.x), "v"(fb.y));
    asm("v_cvt_pk_bf16_f32 %0, %1, %2" : "=v"(r.u[3]) : "v"(fb.z), "v"(fb.w));
    return r.v;
}

// Coherent (LLC-level) 16B load: bypasses L1+L2 so cross-XCD producer data is seen.
// Caller must s_waitcnt vmcnt(0) + sched_barrier(0) before use (rule #18).
__device__ __forceinline__ void load_coh_b128(bf16x8* dst, const void* p) {
    asm volatile("global_load_dwordx4 %0, %1, off sc0 sc1" : "=v"(*dst) : "v"(p));
}

// Pinned (non-rematerializable) 16B load for weights.
__device__ __forceinline__ void load_pin_b128(bf16x8* dst, const void* p) {
    asm volatile("global_load_dwordx4 %0, %1, off" : "=v"(*dst) : "v"(p));
}

// Gate permutation: column p = gt*16 + q*4 + (h&3), gt = h>>2 (tile of 4 hids),
// q = gate (0=i,1=f,2=g,3=o). All 4 gates of a hid live in ONE 16-col tile.
// Packed B-frag: WB[gt][kc][lane][j] = Wcat[p = gt*16 + (lane&15)][k = kc*32 + (lane>>4)*8 + j],
// Wcat[p][k] = k<512 ? Wih[row(p)][k] : Whh[row(p)][k-512].
__global__ __launch_bounds__(256) void lstm_prep(
    const float* __restrict__ Wih, const float* __restrict__ Whh,
    const float* __restrict__ bih, const float* __restrict__ bhh,
    const float* __restrict__ h_prev,
    u16* __restrict__ WB, float* __restrict__ bias_p,
    u16* __restrict__ h0, unsigned* __restrict__ flags)
{
    int idx = blockIdx.x * 256 + threadIdx.x;
    if (idx < WB_ELEMS) {
        int j    = idx & 7;
        int lane = (idx >> 3) & 63;
        int kc   = (idx >> 9) & 31;
        int gt   = idx >> 14;
        int p = gt * 16 + (lane & 15);
        int k = kc * 32 + (lane >> 4) * 8 + j;
        int q = (p >> 2) & 3;
        int h = (p >> 4) * 4 + (p & 3);
        int row = q * 512 + h;
        float v = (k < 512) ? Wih[row * 512 + k] : Whh[row * 512 + (k - 512)];
        WB[idx] = f2bf(v);
    } else if (idx < WB_ELEMS + 2048) {
        int p = idx - WB_ELEMS;
        int q = (p >> 2) & 3;
        int h = (p >> 4) * 4 + (p & 3);
        int row = q * 512 + h;
        bias_p[p] = bih[row] + bhh[row];
    } else if (idx < WB_ELEMS + 2048 + 32768) {
        int i = idx - (WB_ELEMS + 2048);
        h0[i] = f2bf(h_prev[i]);
    } else if (idx < WB_ELEMS + 2048 + 32768 + 512) {
        flags[idx - (WB_ELEMS + 2048 + 32768)] = 0u;
    }
}

// Optional: convert x to bf16 once (halves per-step x traffic, removes per-step cvt).
__global__ __launch_bounds__(256) void x_to_bf16(
    const float* __restrict__ x, u16* __restrict__ xb, int n8)
{
    int i = blockIdx.x * 256 + threadIdx.x;
    if (i < n8) {
        float4 fa = ((const float4*)x)[(size_t)i * 2];
        float4 fb = ((const float4*)x)[(size_t)i * 2 + 1];
        ((bf16x8*)xb)[i] = pack8(fa, fb);
    }
}

// Persistent LSTM. 128 blocks x 4 waves. Block b: batch-tile bt = b&3 (rows 16bt..),
// wave owns n-tile gt = (b>>2)*4 + wv (0..127) = hids 4gt..4gt+4, all 4 gates.
// Weights: 128 VGPR/lane, asm-pinned, loaded once. c-state: 1 reg/lane.
// Sync: per-WAVE monotonic flags (no atomics, no __syncthreads in loop).
// h exchanged via write-through (sc0 sc1) stores + coherent bypass loads.
__global__ __launch_bounds__(256, 1) void lstm_persist(
    const float* __restrict__ x_all, const u16* __restrict__ xbf, int xmode,
    const u16* __restrict__ WB, const float* __restrict__ bias_p,
    const float* __restrict__ c_prev,
    u16* __restrict__ h0, u16* __restrict__ h1, unsigned* __restrict__ flags,
    float* __restrict__ out, float* __restrict__ hf, float* __restrict__ cf)
{
    const int tid  = threadIdx.x;
    const int lane = tid & 63;
    const int wv   = tid >> 6;
    const int b    = blockIdx.x;
    const int bt   = b & 3;
    const int gt   = (b >> 2) * 4 + wv;   // n-tile 0..127
    const int b0   = bt * 16;
    const int col  = lane & 15;
    const int quad = lane >> 4;
    const bool qa  = (col & 4) != 0;      // gate bit 0
    const bool qb  = (col & 8) != 0;      // gate bit 1
    const int q    = col >> 2;
    const int hl   = col & 3;

    unsigned* gflags = flags + bt * 128;                  // this group's 128 wave flags
    unsigned* myflag = gflags + gt;
    const unsigned long long* pollp =
        (const unsigned long long*)gflags + lane;         // 2 flags per lane

    // ---- weights -> registers (once): 32 KB/wave = 128 VGPR/lane, asm-pinned ----
    bf16x8 wx[16], wh[16];
    {
        const u16* wb = WB + (size_t)gt * (32 * 64 * 8) + lane * 8;
#pragma unroll
        for (int kc = 0; kc < 16; ++kc) {
            load_pin_b128(&wx[kc], wb + (size_t)kc * 512);
            load_pin_b128(&wh[kc], wb + (size_t)(kc + 16) * 512);
        }
        asm volatile("s_waitcnt vmcnt(0)" ::: "memory");
        __builtin_amdgcn_sched_barrier(0);
    }

    const float bmy = bias_p[gt * 16 + col];
    const int hid   = gt * 4 + hl;
    const int myrow = quad * 4 + q;              // this lane's C-row within tile
    const int idx   = (b0 + myrow) * 512 + hid;  // cell index in [64][512]
    float c = c_prev[idx];

    const int ba = b0 + col;                     // A-frag row m = lane&15
    const u16* h0row = h0 + ba * 512 + quad * 8;
    const u16* h1row = h1 + ba * 512 + quad * 8;

    for (int t = 0; t < SS; ++t) {
        f32x4 accX = {0.f, 0.f, 0.f, 0.f};

        // ---- x-part (independent of recurrence; overlaps barrier slack) ----
        if (xmode) {
            const u16* xr = xbf + ((size_t)t * BB + ba) * 512 + quad * 8;
#pragma unroll
            for (int kc = 0; kc < 16; ++kc) {
                bf16x8 a = *(const bf16x8*)(xr + kc * 32);
                accX = __builtin_amdgcn_mfma_f32_16x16x32_bf16(a, wx[kc], accX, 0, 0, 0);
                if ((kc & 7) == 7) __builtin_amdgcn_sched_barrier(0);  // cap in-flight regs
            }
        } else {
            const float* xr = x_all + ((size_t)t * BB + ba) * 512 + quad * 8;
#pragma unroll
            for (int kc = 0; kc < 16; ++kc) {
                float4 fa = *(const float4*)(xr + kc * 32);
                float4 fb = *(const float4*)(xr + kc * 32 + 4);
                bf16x8 a = pack8(fa, fb);
                accX = __builtin_amdgcn_mfma_f32_16x16x32_bf16(a, wx[kc], accX, 0, 0, 0);
                if ((kc & 3) == 3) __builtin_amdgcn_sched_barrier(0);  // cap in-flight regs
            }
        }

        // ---- wait for h_{t-1}: all 64 lanes poll 2 flags each (128 producer waves) ----
        if (t) {
            const unsigned tgt = (unsigned)t;
            unsigned guard = 0;
            bool ok;
            do {
                unsigned long long v = __hip_atomic_load(
                    pollp, __ATOMIC_RELAXED, __HIP_MEMORY_SCOPE_AGENT);
                ok = ((unsigned)v >= tgt) && ((unsigned)(v >> 32) >= tgt);
                if (++guard > (1u << 22)) break;   // fail loud, never deadlock
            } while (!__all((int)ok));
        }

        // ---- h-part: coherent loads (bypass L1/L2 -> always fresh), then MFMA ----
        const u16* hr = ((t & 1) ? h1row : h0row);
        bf16x8 hA[16];
#pragma unroll
        for (int kc = 0; kc < 16; ++kc)
            load_coh_b128(&hA[kc], hr + kc * 32);
        asm volatile("s_waitcnt vmcnt(0)" ::: "memory");
        __builtin_amdgcn_sched_barrier(0);   // rule #18: keep MFMAs after the wait
        f32x4 accA = {0.f, 0.f, 0.f, 0.f};
        f32x4 accB = {0.f, 0.f, 0.f, 0.f};
#pragma unroll
        for (int kc = 0; kc < 16; kc += 2) {          // two chains halve MFMA latency
            accA = __builtin_amdgcn_mfma_f32_16x16x32_bf16(hA[kc],     wh[kc],     accA, 0, 0, 0);
            accB = __builtin_amdgcn_mfma_f32_16x16x32_bf16(hA[kc + 1], wh[kc + 1], accB, 0, 0, 0);
        }

        // ---- epilogue: gather 4 gates per cell via 3 shfl_xor; 1 cell/lane ----
        float a0 = accX[0] + accA[0] + accB[0] + bmy;
        float a1 = accX[1] + accA[1] + accB[1] + bmy;
        float a2 = accX[2] + accA[2] + accB[2] + bmy;
        float a3 = accX[3] + accA[3] + accB[3] + bmy;
        // send a[q^k] so partner (q^k) receives its gate at ITS row
        float s1 = qb ? (qa ? a2 : a3) : (qa ? a0 : a1);   // a[q^1]
        float s2 = qb ? (qa ? a1 : a0) : (qa ? a3 : a2);   // a[q^2]
        float s3 = qb ? (qa ? a0 : a1) : (qa ? a2 : a3);   // a[q^3]
        float v0 = qb ? (qa ? a3 : a2) : (qa ? a1 : a0);   // a[q] (own gate, own row)
        float v1 = __shfl_xor(s1, 4);                      // gate q^1 at my row
        float v2 = __shfl_xor(s2, 8);                      // gate q^2
        float v3 = __shfl_xor(s3, 12);                     // gate q^3
        float gi = qb ? (qa ? v3 : v2) : (qa ? v1 : v0);
        float gf = qb ? (qa ? v2 : v3) : (qa ? v0 : v1);
        float gg = qb ? (qa ? v1 : v0) : (qa ? v3 : v2);
        float go = qb ? (qa ? v0 : v1) : (qa ? v2 : v3);

        float i_ = 1.f / (1.f + __expf(-gi));
        float f_ = 1.f / (1.f + __expf(-gf));
        float g_ = 2.f / (1.f + __expf(-2.f * gg)) - 1.f;
        float o_ = 1.f / (1.f + __expf(-go));
        c = f_ * c + i_ * g_;
        float tc = 2.f / (1.f + __expf(-2.f * c)) - 1.f;
        float hnew = o_ * tc;

        // ---- h store (write-through), drain, flag; out store OFF the chain ----
        u16* hout = (t & 1) ? h0 : h1;
        __hip_atomic_store(hout + idx, f2bf(hnew), __ATOMIC_RELAXED, __HIP_MEMORY_SCOPE_AGENT);
        asm volatile("s_waitcnt vmcnt(0)" ::: "memory");
        __hip_atomic_store(myflag, (unsigned)(t + 1), __ATOMIC_RELAXED, __HIP_MEMORY_SCOPE_AGENT);
        out[(size_t)t * (BB * HH) + idx] = hnew;   // cached store: LLC assembles full lines
        if (t == SS - 1) { hf[idx] = hnew; cf[idx] = c; }
    }
}

extern "C" void kernel_launch(void* const* d_in, const int* in_sizes, int n_in,
                              void* d_out, int out_size, void* d_ws, size_t ws_size,
                              hipStream_t stream) {
    const float* x      = (const float*)d_in[0];
    const float* h_prev = (const float*)d_in[1];
    const float* c_prev = (const float*)d_in[2];
    const float* Wih    = (const float*)d_in[3];
    const float* Whh    = (const float*)d_in[4];
    const float* bih    = (const float*)d_in[5];
    const float* bhh    = (const float*)d_in[6];
    float* out = (float*)d_out;

    if (ws_size < WS_BASE) return;  // cannot run without scratch

    char* ws = (char*)d_ws;
    u16*      WB     = (u16*)ws;
    float*    bias_p = (float*)(ws + OFF_BIAS);
    u16*      h0     = (u16*)(ws + OFF_H0);
    u16*      h1     = (u16*)(ws + OFF_H1);
    unsigned* flags  = (unsigned*)(ws + OFF_FLG);
    u16*      xbf    = (u16*)(ws + OFF_XBF);
    int xmode = (ws_size >= WS_XBF) ? 1 : 0;

    int prep_threads = WB_ELEMS + 2048 + 32768 + 512;
    int prep_blocks = (prep_threads + 255) / 256;
    hipLaunchKernelGGL(lstm_prep, dim3(prep_blocks), dim3(256), 0, stream,
                       Wih, Whh, bih, bhh, h_prev, WB, bias_p, h0, flags);

    if (xmode) {
        int n8 = SS * BB * 512 / 8;
        hipLaunchKernelGGL(x_to_bf16, dim3((n8 + 255) / 256), dim3(256), 0, stream,
                           x, xbf, n8);
    }

    float* hf = out + (size_t)SS * BB * HH;
    float* cf = hf + BB * HH;

    void* args[] = {
        (void*)&x, (void*)&xbf, (void*)&xmode, (void*)&WB, (void*)&bias_p,
        (void*)&c_prev, (void*)&h0, (void*)&h1, (void*)&flags,
        (void*)&out, (void*)&hf, (void*)&cf
    };
    hipError_t err = hipLaunchCooperativeKernel(
        reinterpret_cast<void*>(lstm_persist), dim3(128), dim3(256), args, 0, stream);
    if (err != hipSuccess) {
        // 128 blocks x 256 thr = 1 block/CU on a 256-CU idle chip: co-resident anyway.
        hipLaunchKernelGGL(lstm_persist, dim3(128), dim3(256), 0, stream,
                           x, xbf, xmode, WB, bias_p, c_prev, h0, h1, flags, out, hf, cf);
    }
}